// Round 9
// baseline (10206.684 us; speedup 1.0000x reference)
//
#include <hip/hip_runtime.h>
#include <math.h>

typedef unsigned short u16;

__device__ __forceinline__ float bf2f(u16 u) {
  union { float f; unsigned int i; } v; v.i = ((unsigned int)u) << 16; return v.f;
}
__device__ __forceinline__ u16 f2bf(float f) {
  union { float f; unsigned int i; } v; v.f = f;
  unsigned int i = v.i;
  return (u16)((i + 0x7FFFu + ((i >> 16) & 1u)) >> 16);  // RNE
}

// Y[r0+r][c] = sum_k X[r0+r][k] * W[c][k] + bias[c]   (NT gemm, fp32 math)
// X fp32, W/bias fp32, Y bf16. Block: 256 threads, 4 rows x 1024 cols.
__global__ __launch_bounds__(256) void proj_f32_bf16(const float* X, const float* W,
                                                     const float* bias, u16* Y) {
  __shared__ float Xs[4][1024];
  const int t = threadIdx.x, r0 = blockIdx.x * 4;
  for (int i = 0; i < 16; i++) {
    int idx = t + i * 256; int r = idx >> 10, c = idx & 1023;
    Xs[r][c] = X[(r0 + r) * 1024 + c];
  }
  __syncthreads();
  float acc[4][4] = {};  // [row r][col j], col = 4t+j
  for (int k = 0; k < 1024; k += 4) {
    float4 w[4];
#pragma unroll
    for (int j = 0; j < 4; j++)
      w[j] = *reinterpret_cast<const float4*>(&W[(4 * t + j) * 1024 + k]);
#pragma unroll
    for (int r = 0; r < 4; r++) {
      const float4 x = *reinterpret_cast<const float4*>(&Xs[r][k]);
#pragma unroll
      for (int j = 0; j < 4; j++)
        acc[r][j] += x.x * w[j].x + x.y * w[j].y + x.z * w[j].z + x.w * w[j].w;
    }
  }
#pragma unroll
  for (int r = 0; r < 4; r++)
#pragma unroll
    for (int j = 0; j < 4; j++)
      Y[(r0 + r) * 1024 + 4 * t + j] = f2bf(acc[r][j] + bias[4 * t + j]);
}

// Final projection: X bf16 [4096][1024], W/bias fp32, OUTPUT FP32 (the
// reference's output dtype). Same blocking.
__global__ __launch_bounds__(256) void proj_bf16_f32(const u16* X, const float* W,
                                                     const float* bias, float* Y) {
  __shared__ float Xs[4][1024];
  const int t = threadIdx.x, r0 = blockIdx.x * 4;
  for (int i = 0; i < 16; i++) {
    int idx = t + i * 256; int r = idx >> 10, c = idx & 1023;
    Xs[r][c] = bf2f(X[(r0 + r) * 1024 + c]);
  }
  __syncthreads();
  float acc[4][4] = {};
  for (int k = 0; k < 1024; k += 4) {
    float4 w[4];
#pragma unroll
    for (int j = 0; j < 4; j++)
      w[j] = *reinterpret_cast<const float4*>(&W[(4 * t + j) * 1024 + k]);
#pragma unroll
    for (int r = 0; r < 4; r++) {
      const float4 x = *reinterpret_cast<const float4*>(&Xs[r][k]);
#pragma unroll
      for (int j = 0; j < 4; j++)
        acc[r][j] += x.x * w[j].x + x.y * w[j].y + x.z * w[j].z + x.w * w[j].w;
    }
  }
#pragma unroll
  for (int r = 0; r < 4; r++)
#pragma unroll
    for (int j = 0; j < 4; j++)
      Y[(r0 + r) * 1024 + 4 * t + j] = acc[r][j] + bias[4 * t + j];
}

// Interleaved RoPE in place on a [nrows][1024] bf16 buffer. s = row & 2047.
// Pair j within each 64-col head: angle = s * 10000^(-j/32).
__global__ __launch_bounds__(256) void rope(u16* P, float scale) {
  const int idx = blockIdx.x * 256 + threadIdx.x;
  const int row = idx >> 7, cg = idx & 127;
  const int s = row & 2047;
  const int col0 = cg * 8;
  const int j0 = (col0 & 63) >> 1;
  u16* p = &P[row * 1024 + col0];
  float vals[8];
#pragma unroll
  for (int i = 0; i < 8; i++) vals[i] = bf2f(p[i]);
#pragma unroll
  for (int q = 0; q < 4; q++) {
    const int j = j0 + q;
    const float inv = exp2f(-(float)j * (13.287712379549449f / 32.0f));  // 10000^(-j/32)
    const float ang = (float)s * inv;
    float sn, cs;
    sincosf(ang, &sn, &cs);
    const float e = vals[2 * q], o = vals[2 * q + 1];
    p[2 * q]     = f2bf((e * cs - o * sn) * scale);
    p[2 * q + 1] = f2bf((o * cs + e * sn) * scale);
  }
}

// VALU attention for batch b. Grid (2048 query positions, 16 heads), 256 threads.
// Q: [4096][1024] bf16, rope'd, pre-scaled by 1/8. K,V: per-batch [2048][1024] bf16.
// Output in place over Q[row][h*64..h*64+63] — block-private region, race-free.
__global__ __launch_bounds__(256) void attn(u16* Q, const u16* K, const u16* V, int b) {
  __shared__ float sarr[2048];
  __shared__ float q[64];
  __shared__ float red[256];
  const int s0 = blockIdx.x;
  const int h = blockIdx.y;
  const int t = threadIdx.x;
  const int row = b * 2048 + s0;
  u16* qrow = &Q[row * 1024 + h * 64];

  if (t < 64) q[t] = bf2f(qrow[t]);
  __syncthreads();

  float mloc = -1.0e30f;
  for (int key = t; key < 2048; key += 256) {
    const u16* kr = &K[key * 1024 + h * 64];
    float acc = 0.0f;
    for (int d = 0; d < 64; d++) acc += q[d] * bf2f(kr[d]);
    sarr[key] = acc;
    mloc = fmaxf(mloc, acc);
  }
  red[t] = mloc; __syncthreads();
  for (int off = 128; off > 0; off >>= 1) {
    if (t < off) red[t] = fmaxf(red[t], red[t + off]);
    __syncthreads();
  }
  const float m = red[0]; __syncthreads();

  float lloc = 0.0f;
  for (int key = t; key < 2048; key += 256) {
    const float p = __expf(sarr[key] - m);
    sarr[key] = p;
    lloc += p;
  }
  red[t] = lloc; __syncthreads();
  for (int off = 128; off > 0; off >>= 1) {
    if (t < off) red[t] += red[t + off];
    __syncthreads();
  }
  const float l = red[0]; __syncthreads();

  const int g = t >> 6, d = t & 63;
  float acc = 0.0f;
  for (int key = g; key < 2048; key += 4)
    acc += sarr[key] * bf2f(V[key * 1024 + h * 64 + d]);
  red[t] = acc; __syncthreads();
  if (g == 0)
    qrow[d] = f2bf((red[d] + red[64 + d] + red[128 + d] + red[192 + d]) / l);
}

extern "C" void kernel_launch(void* const* d_in, const int* in_sizes, int n_in,
                              void* d_out, int out_size, void* d_ws, size_t ws_size,
                              hipStream_t stream) {
  (void)in_sizes; (void)n_in; (void)out_size; (void)ws_size;
  // Axioms (R0-R8 evidence): inputs fp32, dict order; OUTPUT FP32 (reference
  // returns float32; "bf16" in the test label is a hard-coded string).
  const float* query = (const float*)d_in[0];
  const float* key   = (const float*)d_in[1];
  const float* value = (const float*)d_in[2];
  const float* Wq = (const float*)d_in[3];
  const float* bq = (const float*)d_in[4];
  const float* Wk = (const float*)d_in[5];
  const float* bk = (const float*)d_in[6];
  const float* Wv = (const float*)d_in[7];
  const float* bv = (const float*)d_in[8];
  const float* Wo = (const float*)d_in[9];
  const float* bo = (const float*)d_in[10];

  // d_out is fp32 [4096][1024] = 16 MB. Its lower 8 MB hosts per-batch bf16
  // K/V scratch (dead before the final fp32 write). ws hosts Qs (8 MB bf16),
  // which becomes the attention output in place.
  u16* Qs = (u16*)d_ws;                    // [4096][1024] bf16
  u16* Kd = (u16*)d_out;                   // [2048][1024] bf16 (per batch)
  u16* Vd = (u16*)d_out + 2097152;         // [2048][1024] bf16 (per batch)
  float* out = (float*)d_out;

  // Q projection (all rows) + RoPE (scale folds 1/sqrt(64))
  proj_f32_bf16<<<dim3(1024), dim3(256), 0, stream>>>(query, Wq, bq, Qs);
  rope<<<dim3(2048), dim3(256), 0, stream>>>(Qs, 0.125f);

  for (int b = 0; b < 2; b++) {
    proj_f32_bf16<<<dim3(512), dim3(256), 0, stream>>>(key + (size_t)b * 2048 * 1024, Wk, bk, Kd);
    rope<<<dim3(1024), dim3(256), 0, stream>>>(Kd, 1.0f);
    proj_f32_bf16<<<dim3(512), dim3(256), 0, stream>>>(value + (size_t)b * 2048 * 1024, Wv, bv, Vd);
    attn<<<dim3(2048, 16), dim3(256), 0, stream>>>(Qs, Kd, Vd, b);
  }

  // Final projection: bf16 attention output -> FP32 d_out (overwrites K/V scratch).
  proj_bf16_f32<<<dim3(1024), dim3(256), 0, stream>>>(Qs, Wo, bo, out);
}

// Round 10
// 411.064 us; speedup vs baseline: 24.8299x; 24.8299x over previous
//
#include <hip/hip_runtime.h>
#include <math.h>

typedef unsigned short u16;
typedef __bf16 bf16x8 __attribute__((ext_vector_type(8)));
typedef float floatx4 __attribute__((ext_vector_type(4)));

#define MFMA16(a, b, c) __builtin_amdgcn_mfma_f32_16x16x32_bf16((a), (b), (c), 0, 0, 0)

__device__ __forceinline__ float bf2f(u16 u) {
  union { float f; unsigned int i; } v; v.i = ((unsigned int)u) << 16; return v.f;
}
__device__ __forceinline__ u16 f2bf(float f) {
  union { float f; unsigned int i; } v; v.f = f;
  unsigned int i = v.i;
  return (u16)((i + 0x7FFFu + ((i >> 16) & 1u)) >> 16);  // RNE
}

struct GemmArgs {
  const void* A[3];     // fp32 [4096,1024] (or bf16 if a_bf16)
  const float* W[3];    // fp32 [1024,1024], used as B^T (NT gemm)
  const float* bias[3]; // fp32 [1024]
  void* C[3];           // bf16 or fp32 per out_mode
  int a_bf16[3];
  int out_mode[3];      // 0 = bf16, 1 = bf16 transposed Vt[b,h,d,s], 2 = fp32
};

// C[4096,1024] = A[4096,1024] * W[1024,1024]^T + bias   (fp32 acc)
// 128x128 tile, BK=32, 4 waves x (4x4) 16x16x32 MFMA frags.
__global__ __launch_bounds__(256) void gemm_nt(GemmArgs args) {
  const int N = 1024, K = 1024;
  const int z = blockIdx.z;
  const float* Af = (const float*)args.A[z];
  const u16* Ab = (const u16*)args.A[z];
  const float* W = args.W[z];
  const float* bias = args.bias[z];
  const int a_bf16 = args.a_bf16[z];
  const int out_mode = args.out_mode[z];

  __shared__ u16 As[128][32];  // 64 B rows: every quad*16 b128 read is aligned
  __shared__ u16 Bs[128][32];

  const int t = threadIdx.x;
  const int wave = t >> 6, lane = t & 63;
  const int lr = lane & 15, quad = lane >> 4;
  const int wm = (wave >> 1) * 64, wn = (wave & 1) * 64;
  const int m0 = blockIdx.y * 128, n0 = blockIdx.x * 128;

  floatx4 acc[4][4] = {};

  for (int kt = 0; kt < K; kt += 32) {
    __syncthreads();
    if (a_bf16) {
#pragma unroll
      for (int i = 0; i < 2; i++) {
        int c = t + i * 256;
        int r = c >> 2, ch = c & 3;  // 128 rows x 4 x16B chunks (8 bf16)
        *reinterpret_cast<uint4*>(&As[r][ch * 8]) =
            *reinterpret_cast<const uint4*>(&Ab[(m0 + r) * K + kt + ch * 8]);
      }
    } else {
#pragma unroll
      for (int i = 0; i < 4; i++) {
        int c = t + i * 256;
        int r = c >> 3, ch = c & 7;  // 128 rows x 8 float4 chunks (4 fp32)
        const float4 v = *reinterpret_cast<const float4*>(&Af[(m0 + r) * K + kt + ch * 4]);
        ushort4 pk;
        pk.x = f2bf(v.x); pk.y = f2bf(v.y); pk.z = f2bf(v.z); pk.w = f2bf(v.w);
        *reinterpret_cast<ushort4*>(&As[r][ch * 4]) = pk;
      }
    }
#pragma unroll
    for (int i = 0; i < 4; i++) {
      int c = t + i * 256;
      int r = c >> 3, ch = c & 7;
      const float4 v = *reinterpret_cast<const float4*>(&W[(n0 + r) * K + kt + ch * 4]);
      ushort4 pk;
      pk.x = f2bf(v.x); pk.y = f2bf(v.y); pk.z = f2bf(v.z); pk.w = f2bf(v.w);
      *reinterpret_cast<ushort4*>(&Bs[r][ch * 4]) = pk;
    }
    __syncthreads();

    bf16x8 af[4], bf[4];
#pragma unroll
    for (int i = 0; i < 4; i++) {
      af[i] = *reinterpret_cast<const bf16x8*>(&As[wm + i * 16 + lr][quad * 8]);
      bf[i] = *reinterpret_cast<const bf16x8*>(&Bs[wn + i * 16 + lr][quad * 8]);
    }
#pragma unroll
    for (int mi = 0; mi < 4; mi++)
#pragma unroll
      for (int nf = 0; nf < 4; nf++)
        acc[mi][nf] = MFMA16(af[mi], bf[nf], acc[mi][nf]);
  }

  // epilogue: C-frag mapping col = lane&15, row = quad*4 + reg (m89/m91)
#pragma unroll
  for (int nf = 0; nf < 4; nf++) {
    const int col = n0 + wn + nf * 16 + lr;
    const float bv = bias[col];
#pragma unroll
    for (int mi = 0; mi < 4; mi++) {
      const int row0 = m0 + wm + mi * 16 + quad * 4;
      if (out_mode == 0) {
        u16* C = (u16*)args.C[z];
#pragma unroll
        for (int r = 0; r < 4; r++)
          C[(row0 + r) * N + col] = f2bf(acc[mi][nf][r] + bv);
      } else if (out_mode == 1) {
        u16* C = (u16*)args.C[z];
        const int h = col >> 6, d = col & 63;
        const int b = row0 >> 11, s = row0 & 2047;
        ushort4 pk;
        pk.x = f2bf(acc[mi][nf][0] + bv);
        pk.y = f2bf(acc[mi][nf][1] + bv);
        pk.z = f2bf(acc[mi][nf][2] + bv);
        pk.w = f2bf(acc[mi][nf][3] + bv);
        *reinterpret_cast<ushort4*>(&C[((b * 16 + h) * 64 + d) * 2048 + s]) = pk;
      } else {
        float* C = (float*)args.C[z];
#pragma unroll
        for (int r = 0; r < 4; r++)
          C[(row0 + r) * N + col] = acc[mi][nf][r] + bv;
      }
    }
  }
}

// Interleaved RoPE on Q and K in-place (bf16); folds 1/sqrt(D)=0.125 into Q.
__global__ __launch_bounds__(256) void rope_kernel(u16* Q, u16* Kb) {
  const int idx = blockIdx.x * 256 + threadIdx.x;  // 0 .. 2*4096*128-1
  const int tensor = idx >> 19;
  const int i = idx & 524287;
  u16* P = tensor ? Kb : Q;
  const int row = i >> 7;        // b*2048+s
  const int cg = i & 127;        // 8-col group
  const int s = row & 2047;
  const int col0 = cg * 8;
  const float scale = tensor ? 1.0f : 0.125f;
  union { uint4 u; u16 h[8]; } v;
  v.u = *reinterpret_cast<const uint4*>(&P[row * 1024 + col0]);
  const int j0 = (col0 & 63) >> 1;
#pragma unroll
  for (int p = 0; p < 4; p++) {
    const int j = j0 + p;
    const float inv = exp2f(-(float)j * (13.287712379549449f / 32.0f));  // 10000^(-j/32)
    const float f = (float)s * inv;
    float sn, cs;
    sincosf(f, &sn, &cs);
    const float e = bf2f(v.h[2 * p]), o = bf2f(v.h[2 * p + 1]);
    v.h[2 * p]     = f2bf((e * cs - o * sn) * scale);
    v.h[2 * p + 1] = f2bf((o * cs + e * sn) * scale);
  }
  *reinterpret_cast<uint4*>(&P[row * 1024 + col0]) = v.u;
}

// Flash attention: grid (32 q-blocks, 32 b*h), 256 thr; wave w owns 16 q-rows.
// Q pre-scaled by 1/8. Vt is [b,h,d,s]. O aliases Q (wave-private region: the
// wave reads its 16 rows x 64 head-cols into registers before the loop and
// writes exactly that region after).
__global__ __launch_bounds__(256) void attn_kernel(const u16* Q, const u16* K,
                                                   const u16* Vt, u16* O) {
  const int bh = blockIdx.y;
  const int b = bh >> 4, h = bh & 15;
  const int t = threadIdx.x;
  const int wave = t >> 6, lane = t & 63;
  const int lr = lane & 15, quad = lane >> 4;

  __shared__ u16 Ks[64][72];      // [key][d]  (144 B rows: b128 aligned)
  __shared__ u16 Vs[64][72];      // [d][key]  (V^T tile)
  __shared__ u16 Ps[4][16][72];   // per-wave P: [qrow][key]

  const int qrow0 = blockIdx.x * 64 + wave * 16;
  const u16* qptr = &Q[(b * 2048 + qrow0) * 1024 + h * 64];
  const bf16x8 qf0 = *reinterpret_cast<const bf16x8*>(&qptr[lr * 1024 + quad * 8]);
  const bf16x8 qf1 = *reinterpret_cast<const bf16x8*>(&qptr[lr * 1024 + 32 + quad * 8]);

  const u16* kptr = &K[b * 2048 * 1024 + h * 64];
  const u16* vptr = &Vt[bh * 64 * 2048];

  floatx4 o_acc[4] = {};
  float m_r[4], l_r[4];
#pragma unroll
  for (int r = 0; r < 4; r++) { m_r[r] = -1.0e30f; l_r[r] = 0.0f; }

  for (int kt = 0; kt < 2048; kt += 64) {
    __syncthreads();
#pragma unroll
    for (int i = 0; i < 2; i++) {
      int c = t + i * 256;
      int r = c >> 3, ch = c & 7;  // 64 rows x 8 x16B chunks
      *reinterpret_cast<uint4*>(&Ks[r][ch * 8]) =
          *reinterpret_cast<const uint4*>(&kptr[(kt + r) * 1024 + ch * 8]);
      *reinterpret_cast<uint4*>(&Vs[r][ch * 8]) =
          *reinterpret_cast<const uint4*>(&vptr[r * 2048 + kt + ch * 8]);
    }
    __syncthreads();

    // S = Q K^T: 4 key-subtiles x 2 k-chunks
    floatx4 sc[4];
#pragma unroll
    for (int nf = 0; nf < 4; nf++) {
      bf16x8 b0 = *reinterpret_cast<const bf16x8*>(&Ks[nf * 16 + lr][quad * 8]);
      bf16x8 b1 = *reinterpret_cast<const bf16x8*>(&Ks[nf * 16 + lr][32 + quad * 8]);
      floatx4 a = {};
      a = MFMA16(qf0, b0, a);
      a = MFMA16(qf1, b1, a);
      sc[nf] = a;
    }

    // online softmax; quad-row r spread across the 16 lanes of the quad
    float alpha[4];
#pragma unroll
    for (int r = 0; r < 4; r++) {
      float mx = fmaxf(fmaxf(sc[0][r], sc[1][r]), fmaxf(sc[2][r], sc[3][r]));
#pragma unroll
      for (int d = 1; d < 16; d <<= 1) mx = fmaxf(mx, __shfl_xor(mx, d, 64));
      const float mn = fmaxf(m_r[r], mx);
      alpha[r] = __expf(m_r[r] - mn);   // underflows to 0 on first tile
      m_r[r] = mn;
      float rs = 0.0f;
#pragma unroll
      for (int nf = 0; nf < 4; nf++) {
        sc[nf][r] = __expf(sc[nf][r] - mn);
        rs += sc[nf][r];
      }
#pragma unroll
      for (int d = 1; d < 16; d <<= 1) rs += __shfl_xor(rs, d, 64);
      l_r[r] = l_r[r] * alpha[r] + rs;
#pragma unroll
      for (int nf = 0; nf < 4; nf++) o_acc[nf][r] *= alpha[r];
    }

    // P: C-layout -> LDS -> A-layout (m120 round trip)
#pragma unroll
    for (int nf = 0; nf < 4; nf++)
#pragma unroll
      for (int r = 0; r < 4; r++)
        Ps[wave][quad * 4 + r][nf * 16 + lr] = f2bf(sc[nf][r]);

    __syncthreads();

    const bf16x8 a0 = *reinterpret_cast<const bf16x8*>(&Ps[wave][lr][quad * 8]);
    const bf16x8 a1 = *reinterpret_cast<const bf16x8*>(&Ps[wave][lr][32 + quad * 8]);
#pragma unroll
    for (int nf = 0; nf < 4; nf++) {
      bf16x8 b0 = *reinterpret_cast<const bf16x8*>(&Vs[nf * 16 + lr][quad * 8]);
      bf16x8 b1 = *reinterpret_cast<const bf16x8*>(&Vs[nf * 16 + lr][32 + quad * 8]);
      o_acc[nf] = MFMA16(a0, b0, o_acc[nf]);
      o_acc[nf] = MFMA16(a1, b1, o_acc[nf]);
    }
  }

  u16* optr = &O[(b * 2048 + qrow0) * 1024 + h * 64];
#pragma unroll
  for (int nf = 0; nf < 4; nf++)
#pragma unroll
    for (int r = 0; r < 4; r++)
      optr[(quad * 4 + r) * 1024 + nf * 16 + lr] = f2bf(o_acc[nf][r] / l_r[r]);
}

extern "C" void kernel_launch(void* const* d_in, const int* in_sizes, int n_in,
                              void* d_out, int out_size, void* d_ws, size_t ws_size,
                              hipStream_t stream) {
  (void)in_sizes; (void)n_in; (void)out_size; (void)ws_size;
  // Verified axioms (R9 green): inputs fp32 dict order; output fp32.
  const float* query = (const float*)d_in[0];
  const float* key   = (const float*)d_in[1];
  const float* value = (const float*)d_in[2];
  const float* Wq = (const float*)d_in[3];
  const float* bq = (const float*)d_in[4];
  const float* Wk = (const float*)d_in[5];
  const float* bk = (const float*)d_in[6];
  const float* Wv = (const float*)d_in[7];
  const float* bv = (const float*)d_in[8];
  const float* Wo = (const float*)d_in[9];
  const float* bo = (const float*)d_in[10];

  // Scratch: Qb (8 MB bf16) in ws [R9-verified size]; Kb + Vt (16 MB bf16)
  // inside d_out (16 MB fp32), dead until the final fp32 GEMM overwrites it.
  u16* Qb = (u16*)d_ws;                  // [4096][1024] bf16, attn out in-place
  u16* Kb = (u16*)d_out;                 // [4096][1024] bf16
  u16* Vt = (u16*)d_out + 4194304;       // [2,16,64,2048] bf16

  GemmArgs g1;
  g1.A[0] = query; g1.W[0] = Wq; g1.bias[0] = bq; g1.C[0] = Qb; g1.a_bf16[0] = 0; g1.out_mode[0] = 0;
  g1.A[1] = key;   g1.W[1] = Wk; g1.bias[1] = bk; g1.C[1] = Kb; g1.a_bf16[1] = 0; g1.out_mode[1] = 0;
  g1.A[2] = value; g1.W[2] = Wv; g1.bias[2] = bv; g1.C[2] = Vt; g1.a_bf16[2] = 0; g1.out_mode[2] = 1;
  gemm_nt<<<dim3(8, 32, 3), dim3(256), 0, stream>>>(g1);

  rope_kernel<<<dim3(4096), dim3(256), 0, stream>>>(Qb, Kb);

  // In-place: attention output overwrites Qb (wave-private regions).
  attn_kernel<<<dim3(32, 32), dim3(256), 0, stream>>>(Qb, Kb, Vt, Qb);

  // Final projection: bf16 attn output -> fp32 d_out (+ bias).
  GemmArgs g2;
  for (int i = 0; i < 3; i++) {
    g2.A[i] = Qb; g2.W[i] = Wo; g2.bias[i] = bo;
    g2.C[i] = d_out; g2.a_bf16[i] = 1; g2.out_mode[i] = 2;
  }
  gemm_nt<<<dim3(8, 32, 1), dim3(256), 0, stream>>>(g2);
}

// Round 12
// 329.752 us; speedup vs baseline: 30.9526x; 1.2466x over previous
//
#include <hip/hip_runtime.h>
#include <math.h>

typedef unsigned short u16;
typedef __bf16 bf16x8 __attribute__((ext_vector_type(8)));
typedef float floatx4 __attribute__((ext_vector_type(4)));

#define MFMA16(a, b, c) __builtin_amdgcn_mfma_f32_16x16x32_bf16((a), (b), (c), 0, 0, 0)

__device__ __forceinline__ float bf2f(u16 u) {
  union { float f; unsigned int i; } v; v.i = ((unsigned int)u) << 16; return v.f;
}
__device__ __forceinline__ u16 f2bf(float f) {  // native RNE cvt
  __bf16 h = (__bf16)f;
  union { __bf16 h; u16 u; } v; v.h = h; return v.u;
}
__device__ __forceinline__ bf16x8 cvt8(float4 a, float4 b) {
  bf16x8 r;
  r[0] = (__bf16)a.x; r[1] = (__bf16)a.y; r[2] = (__bf16)a.z; r[3] = (__bf16)a.w;
  r[4] = (__bf16)b.x; r[5] = (__bf16)b.y; r[6] = (__bf16)b.z; r[7] = (__bf16)b.w;
  return r;
}
// Async global->LDS, 16 B per lane. LDS dest = wave-uniform base + lane*16.
__device__ __forceinline__ void gl2lds16(const void* g, void* l) {
  __builtin_amdgcn_global_load_lds(
      (const __attribute__((address_space(1))) unsigned int*)g,
      (__attribute__((address_space(3))) unsigned int*)l, 16, 0, 0);
}

struct GemmArgs {
  const void* A[3];     // fp32 (ABF16=0) or bf16 (ABF16=1) [.,1024]
  const float* W[3];    // fp32 [1024,1024] used as B^T (NT)
  const float* bias[3]; // fp32 [1024]
  void* C[3];
  int out_mode[3];      // 0 = bf16, 1 = bf16 Vt[b,h,d,s], 2 = fp32
};

// C[4096,1024] = A @ W^T + bias, BMx128 tile, BK=32, fp32 acc.
// Staging via global_load_lds (16B/lane); fp32 tiles converted to bf16 at
// fragment-read with native cvt. 16B chunks XOR-swizzled -> conflict-free b128.
template <int BM, int ABF16>
__global__ __launch_bounds__(256) void gemm_nt(GemmArgs args) {
  const int N = 1024, K = 1024;
  const int z = blockIdx.z;
  const float* W = args.W[z];
  const float* bias = args.bias[z];
  const int out_mode = args.out_mode[z];
  constexpr int MI = BM / 32;

  __shared__ __align__(16) char AsB[ABF16 ? BM * 64 : BM * 128];
  __shared__ __align__(16) char BsB[128 * 128];

  const int t = threadIdx.x;
  const int wave = t >> 6, lane = t & 63;
  const int lr = lane & 15, quad = lane >> 4;
  const int wm = (wave >> 1) * (BM / 2), wn = (wave & 1) * 64;
  const int m0 = blockIdx.y * BM, n0 = blockIdx.x * 128;

  floatx4 acc[MI][4] = {};

  for (int kt = 0; kt < K; kt += 32) {
    __syncthreads();
    if constexpr (ABF16) {
      const u16* Ab = (const u16*)args.A[z];
#pragma unroll
      for (int j = 0; j < BM / 64; j++) {
        const int r0 = wave * (BM / 4) + j * 16;
        const int row = r0 + (lane >> 2);
        const int cg = (lane & 3) ^ ((lane >> 2) & 3);
        gl2lds16(Ab + (size_t)(m0 + row) * K + kt + cg * 8, AsB + r0 * 64 + lane * 16);
      }
    } else {
      const float* Af = (const float*)args.A[z];
#pragma unroll
      for (int j = 0; j < BM / 32; j++) {
        const int r0 = wave * (BM / 4) + j * 8;
        const int row = r0 + (lane >> 3);
        const int cg = (lane & 7) ^ ((lane >> 3) & 7);
        gl2lds16(Af + (size_t)(m0 + row) * K + kt + cg * 4, AsB + r0 * 128 + lane * 16);
      }
    }
#pragma unroll
    for (int j = 0; j < 4; j++) {
      const int r0 = wave * 32 + j * 8;
      const int row = r0 + (lane >> 3);
      const int cg = (lane & 7) ^ ((lane >> 3) & 7);
      gl2lds16(W + (size_t)(n0 + row) * K + kt + cg * 4, BsB + r0 * 128 + lane * 16);
    }
    __syncthreads();

    bf16x8 af[MI], bf[4];
#pragma unroll
    for (int i = 0; i < MI; i++) {
      const int row = wm + i * 16 + lr;
      if constexpr (ABF16) {
        const int cp = quad ^ (row & 3);
        af[i] = *reinterpret_cast<const bf16x8*>(AsB + row * 64 + cp * 16);
      } else {
        const int e = row & 7;
        const float4 c0 = *reinterpret_cast<const float4*>(AsB + row * 128 + ((2 * quad) ^ e) * 16);
        const float4 c1 = *reinterpret_cast<const float4*>(AsB + row * 128 + ((2 * quad + 1) ^ e) * 16);
        af[i] = cvt8(c0, c1);
      }
    }
#pragma unroll
    for (int i = 0; i < 4; i++) {
      const int row = wn + i * 16 + lr;
      const int e = row & 7;
      const float4 c0 = *reinterpret_cast<const float4*>(BsB + row * 128 + ((2 * quad) ^ e) * 16);
      const float4 c1 = *reinterpret_cast<const float4*>(BsB + row * 128 + ((2 * quad + 1) ^ e) * 16);
      bf[i] = cvt8(c0, c1);
    }
#pragma unroll
    for (int mi = 0; mi < MI; mi++)
#pragma unroll
      for (int nf = 0; nf < 4; nf++)
        acc[mi][nf] = MFMA16(af[mi], bf[nf], acc[mi][nf]);
  }

  // epilogue: C-frag col = lane&15, row = quad*4 + reg
#pragma unroll
  for (int nf = 0; nf < 4; nf++) {
    const int col = n0 + wn + nf * 16 + lr;
    const float bv = bias[col];
#pragma unroll
    for (int mi = 0; mi < MI; mi++) {
      const int row0 = m0 + wm + mi * 16 + quad * 4;
      if (out_mode == 0) {
        u16* C = (u16*)args.C[z];
#pragma unroll
        for (int r = 0; r < 4; r++)
          C[(row0 + r) * N + col] = f2bf(acc[mi][nf][r] + bv);
      } else if (out_mode == 1) {
        u16* C = (u16*)args.C[z];
        const int h = col >> 6, d = col & 63;
        const int b = row0 >> 11, s = row0 & 2047;
        ushort4 pk;
        pk.x = f2bf(acc[mi][nf][0] + bv);
        pk.y = f2bf(acc[mi][nf][1] + bv);
        pk.z = f2bf(acc[mi][nf][2] + bv);
        pk.w = f2bf(acc[mi][nf][3] + bv);
        *reinterpret_cast<ushort4*>(&C[((b * 16 + h) * 64 + d) * 2048 + s]) = pk;
      } else {
        float* C = (float*)args.C[z];
#pragma unroll
        for (int r = 0; r < 4; r++)
          C[(row0 + r) * N + col] = acc[mi][nf][r] + bv;
      }
    }
  }
}

// Interleaved RoPE on Q and K in-place (bf16); folds 1/sqrt(D)=0.125 into Q.
__global__ __launch_bounds__(256) void rope_kernel(u16* Q, u16* Kb) {
  const int idx = blockIdx.x * 256 + threadIdx.x;
  const int tensor = idx >> 19;
  const int i = idx & 524287;
  u16* P = tensor ? Kb : Q;
  const int row = i >> 7;
  const int cg = i & 127;
  const int s = row & 2047;
  const int col0 = cg * 8;
  const float scale = tensor ? 1.0f : 0.125f;
  union { uint4 u; u16 h[8]; } v;
  v.u = *reinterpret_cast<const uint4*>(&P[row * 1024 + col0]);
  const int j0 = (col0 & 63) >> 1;
#pragma unroll
  for (int p = 0; p < 4; p++) {
    const int j = j0 + p;
    const float inv = exp2f(-(float)j * (13.287712379549449f / 32.0f));  // 10000^(-j/32)
    const float f = (float)s * inv;
    float sn, cs;
    sincosf(f, &sn, &cs);
    const float e = bf2f(v.h[2 * p]), o = bf2f(v.h[2 * p + 1]);
    v.h[2 * p]     = f2bf((e * cs - o * sn) * scale);
    v.h[2 * p + 1] = f2bf((o * cs + e * sn) * scale);
  }
  *reinterpret_cast<uint4*>(&P[row * 1024 + col0]) = v.u;
}

// Flash attention — R10-proven body (online max, 3 barriers/tile). Bisect:
// R11's no-max / dropped-Ps-barrier variant diverged post-timing.
__global__ __launch_bounds__(256) void attn_kernel(const u16* Q, const u16* K,
                                                   const u16* Vt, u16* O) {
  const int bh = blockIdx.y;
  const int b = bh >> 4, h = bh & 15;
  const int t = threadIdx.x;
  const int wave = t >> 6, lane = t & 63;
  const int lr = lane & 15, quad = lane >> 4;

  __shared__ u16 Ks[64][72];
  __shared__ u16 Vs[64][72];
  __shared__ u16 Ps[4][16][72];

  const int qrow0 = blockIdx.x * 64 + wave * 16;
  const u16* qptr = &Q[(b * 2048 + qrow0) * 1024 + h * 64];
  const bf16x8 qf0 = *reinterpret_cast<const bf16x8*>(&qptr[lr * 1024 + quad * 8]);
  const bf16x8 qf1 = *reinterpret_cast<const bf16x8*>(&qptr[lr * 1024 + 32 + quad * 8]);

  const u16* kptr = &K[b * 2048 * 1024 + h * 64];
  const u16* vptr = &Vt[bh * 64 * 2048];

  floatx4 o_acc[4] = {};
  float m_r[4], l_r[4];
#pragma unroll
  for (int r = 0; r < 4; r++) { m_r[r] = -1.0e30f; l_r[r] = 0.0f; }

  for (int kt = 0; kt < 2048; kt += 64) {
    __syncthreads();
#pragma unroll
    for (int i = 0; i < 2; i++) {
      int c = t + i * 256;
      int r = c >> 3, ch = c & 7;
      *reinterpret_cast<uint4*>(&Ks[r][ch * 8]) =
          *reinterpret_cast<const uint4*>(&kptr[(kt + r) * 1024 + ch * 8]);
      *reinterpret_cast<uint4*>(&Vs[r][ch * 8]) =
          *reinterpret_cast<const uint4*>(&vptr[r * 2048 + kt + ch * 8]);
    }
    __syncthreads();

    floatx4 sc[4];
#pragma unroll
    for (int nf = 0; nf < 4; nf++) {
      bf16x8 b0 = *reinterpret_cast<const bf16x8*>(&Ks[nf * 16 + lr][quad * 8]);
      bf16x8 b1 = *reinterpret_cast<const bf16x8*>(&Ks[nf * 16 + lr][32 + quad * 8]);
      floatx4 a = {};
      a = MFMA16(qf0, b0, a);
      a = MFMA16(qf1, b1, a);
      sc[nf] = a;
    }

    float alpha[4];
#pragma unroll
    for (int r = 0; r < 4; r++) {
      float mx = fmaxf(fmaxf(sc[0][r], sc[1][r]), fmaxf(sc[2][r], sc[3][r]));
#pragma unroll
      for (int d = 1; d < 16; d <<= 1) mx = fmaxf(mx, __shfl_xor(mx, d, 64));
      const float mn = fmaxf(m_r[r], mx);
      alpha[r] = __expf(m_r[r] - mn);
      m_r[r] = mn;
      float rs = 0.0f;
#pragma unroll
      for (int nf = 0; nf < 4; nf++) {
        sc[nf][r] = __expf(sc[nf][r] - mn);
        rs += sc[nf][r];
      }
#pragma unroll
      for (int d = 1; d < 16; d <<= 1) rs += __shfl_xor(rs, d, 64);
      l_r[r] = l_r[r] * alpha[r] + rs;
#pragma unroll
      for (int nf = 0; nf < 4; nf++) o_acc[nf][r] *= alpha[r];
    }

#pragma unroll
    for (int nf = 0; nf < 4; nf++)
#pragma unroll
      for (int r = 0; r < 4; r++)
        Ps[wave][quad * 4 + r][nf * 16 + lr] = f2bf(sc[nf][r]);

    __syncthreads();

    const bf16x8 a0 = *reinterpret_cast<const bf16x8*>(&Ps[wave][lr][quad * 8]);
    const bf16x8 a1 = *reinterpret_cast<const bf16x8*>(&Ps[wave][lr][32 + quad * 8]);
#pragma unroll
    for (int nf = 0; nf < 4; nf++) {
      bf16x8 b0 = *reinterpret_cast<const bf16x8*>(&Vs[nf * 16 + lr][quad * 8]);
      bf16x8 b1 = *reinterpret_cast<const bf16x8*>(&Vs[nf * 16 + lr][32 + quad * 8]);
      o_acc[nf] = MFMA16(a0, b0, o_acc[nf]);
      o_acc[nf] = MFMA16(a1, b1, o_acc[nf]);
    }
  }

  u16* optr = &O[(b * 2048 + qrow0) * 1024 + h * 64];
#pragma unroll
  for (int nf = 0; nf < 4; nf++)
#pragma unroll
    for (int r = 0; r < 4; r++)
      optr[(quad * 4 + r) * 1024 + nf * 16 + lr] = f2bf(o_acc[nf][r] / l_r[r]);
}

extern "C" void kernel_launch(void* const* d_in, const int* in_sizes, int n_in,
                              void* d_out, int out_size, void* d_ws, size_t ws_size,
                              hipStream_t stream) {
  (void)in_sizes; (void)n_in; (void)out_size; (void)ws_size;
  const float* query = (const float*)d_in[0];
  const float* key   = (const float*)d_in[1];
  const float* value = (const float*)d_in[2];
  const float* Wq = (const float*)d_in[3];
  const float* bq = (const float*)d_in[4];
  const float* Wk = (const float*)d_in[5];
  const float* bk = (const float*)d_in[6];
  const float* Wv = (const float*)d_in[7];
  const float* bv = (const float*)d_in[8];
  const float* Wo = (const float*)d_in[9];
  const float* bo = (const float*)d_in[10];

  // Qb (8 MB bf16) in ws; Kb + Vt (16 MB bf16) inside d_out (16 MB fp32),
  // dead until the final fp32 GEMM overwrites it.
  u16* Qb = (u16*)d_ws;
  u16* Kb = (u16*)d_out;
  u16* Vt = (u16*)d_out + 4194304;

  GemmArgs g1;
  g1.A[0] = query; g1.W[0] = Wq; g1.bias[0] = bq; g1.C[0] = Qb; g1.out_mode[0] = 0;
  g1.A[1] = key;   g1.W[1] = Wk; g1.bias[1] = bk; g1.C[1] = Kb; g1.out_mode[1] = 0;
  g1.A[2] = value; g1.W[2] = Wv; g1.bias[2] = bv; g1.C[2] = Vt; g1.out_mode[2] = 1;
  gemm_nt<128, 0><<<dim3(8, 32, 3), dim3(256), 0, stream>>>(g1);

  rope_kernel<<<dim3(4096), dim3(256), 0, stream>>>(Qb, Kb);

  attn_kernel<<<dim3(32, 32), dim3(256), 0, stream>>>(Qb, Kb, Vt, Qb);

  // Final projection: bf16 attn output -> fp32 d_out. BM=64 -> 512 blocks.
  GemmArgs g2;
  for (int i = 0; i < 3; i++) {
    g2.A[i] = Qb; g2.W[i] = Wo; g2.bias[i] = bo;
    g2.C[i] = d_out; g2.out_mode[i] = 2;
  }
  gemm_nt<64, 1><<<dim3(8, 64, 1), dim3(256), 0, stream>>>(g2);
}